// Round 5
// baseline (14781.528 us; speedup 1.0000x reference)
//
#include <hip/hip_runtime.h>

#define N_NODES 100000
#define N_EDGES 1200000
#define DIM_IN 128
#define DIM_H 64
#define DIM_H2 128
#define DIM_OUT 112
#define N_LAYERS 7

__device__ __forceinline__ float wsum(float v) {
#pragma unroll
  for (int m = 1; m < 64; m <<= 1) v += __shfl_xor(v, m, 64);
  return v;
}

// ---------------- preprocessing: CSR build (dst-sorted) ----------------

__global__ void k_zero_i(int* __restrict__ p, int n) {
  int i = blockIdx.x * 256 + threadIdx.x;
  if (i < n) p[i] = 0;
}

__global__ void k_hist(const int* __restrict__ dst, int* __restrict__ counts) {
  int e = blockIdx.x * 256 + threadIdx.x;
  if (e < N_EDGES) atomicAdd(&counts[dst[e]], 1);
}

__global__ void k_scan1(const int* __restrict__ counts, int* __restrict__ bsums) {
  __shared__ int sd[256];
  int t = threadIdx.x;
  int i = blockIdx.x * 256 + t;
  sd[t] = (i < N_NODES) ? counts[i] : 0;
  __syncthreads();
  for (int s = 128; s > 0; s >>= 1) {
    if (t < s) sd[t] += sd[t + s];
    __syncthreads();
  }
  if (t == 0) bsums[blockIdx.x] = sd[0];
}

__global__ void k_scan2(int* __restrict__ bsums, int nb) {
  __shared__ int sd[512];
  int t = threadIdx.x;
  int v = (t < nb) ? bsums[t] : 0;
  sd[t] = v;
  __syncthreads();
  for (int o = 1; o < 512; o <<= 1) {
    int add = (t >= o) ? sd[t - o] : 0;
    __syncthreads();
    sd[t] += add;
    __syncthreads();
  }
  if (t < nb) bsums[t] = sd[t] - v;  // exclusive
}

__global__ void k_scan3(const int* __restrict__ counts, const int* __restrict__ bsums,
                        int* __restrict__ offs) {
  __shared__ int sd[256];
  int t = threadIdx.x;
  int i = blockIdx.x * 256 + t;
  int v = (i < N_NODES) ? counts[i] : 0;
  sd[t] = v;
  __syncthreads();
  for (int o = 1; o < 256; o <<= 1) {
    int add = (t >= o) ? sd[t - o] : 0;
    __syncthreads();
    sd[t] += add;
    __syncthreads();
  }
  int excl = sd[t] - v + bsums[blockIdx.x];
  if (i < N_NODES) offs[i] = excl;
  if (i == N_NODES - 1) offs[N_NODES] = excl + v;  // = E
}

__global__ void k_copy_i(const int* __restrict__ a, int* __restrict__ b, int n) {
  int i = blockIdx.x * 256 + threadIdx.x;
  if (i < n) b[i] = a[i];
}

__global__ void k_scatter(const int* __restrict__ src, const int* __restrict__ dst,
                          int* __restrict__ cursor, int* __restrict__ ssrc) {
  int e = blockIdx.x * 256 + threadIdx.x;
  if (e < N_EDGES) {
    int d = dst[e];
    int p = atomicAdd(&cursor[d], 1);
    ssrc[p] = src[e];
  }
}

// ---------------- encoder: h = x @ enc_W + enc_b ----------------
// block 256 = 4 waves, 8 nodes/wave; W staged in LDS (32KB). grid = 3125.

__global__ __launch_bounds__(256, 3) void k_encoder(const float* __restrict__ x,
                                                    const float* __restrict__ W,
                                                    const float* __restrict__ bias,
                                                    float* __restrict__ h) {
  __shared__ float sx[32][DIM_IN];           // 16KB
  __shared__ float sW[DIM_IN * DIM_H];       // 32KB
  int t = threadIdx.x;
  int node0 = blockIdx.x * 32;
  for (int i = t; i < DIM_IN * DIM_H; i += 256) sW[i] = W[i];
  for (int i = t; i < 32 * DIM_IN; i += 256) {
    int r = i >> 7, c = i & 127;
    sx[r][c] = x[(size_t)(node0 + r) * DIM_IN + c];
  }
  __syncthreads();
  int w = t >> 6, lane = t & 63;
  float acc[8];
#pragma unroll
  for (int j = 0; j < 8; j++) acc[j] = 0.f;
  for (int k0 = 0; k0 < DIM_IN; k0 += 4) {
    float w0 = sW[(k0 + 0) * DIM_H + lane];
    float w1 = sW[(k0 + 1) * DIM_H + lane];
    float w2 = sW[(k0 + 2) * DIM_H + lane];
    float w3 = sW[(k0 + 3) * DIM_H + lane];
#pragma unroll
    for (int j = 0; j < 8; j++) {
      float4 a = *(const float4*)&sx[w * 8 + j][k0];
      acc[j] += a.x * w0 + a.y * w1 + a.z * w2 + a.w * w3;
    }
  }
  float bv = bias[lane];
#pragma unroll
  for (int j = 0; j < 8; j++) {
    int v = node0 + w * 8 + j;
    h[(size_t)v * DIM_H + lane] = acc[j] + bv;
  }
}

// ---------------- edge aggregation + MsgNorm ----------------
// wave per node, lane = channel. Per-channel softmax over in-edges is
// lane-local; skip max-subtraction (z = t*(relu(x)+eps) bounded ~8).

__global__ __launch_bounds__(256) void k_edge(const float* __restrict__ xin,
                                              const int* __restrict__ ssrc,
                                              const int* __restrict__ offs,
                                              const float* __restrict__ t_arr,
                                              const float* __restrict__ sc_arr, int layer,
                                              float* __restrict__ hmid) {
  int v = blockIdx.x * 4 + (threadIdx.x >> 6);
  int lane = threadIdx.x & 63;
  float tval = t_arr[layer];
  float sc = sc_arr[layer];
  int beg = offs[v], end = offs[v + 1];
  float xv = xin[(size_t)v * DIM_H + lane];
  float D0 = 0.f, S0 = 0.f, D1 = 0.f, S1 = 0.f;
  int e = beg;
  for (; e + 1 < end; e += 2) {
    int s0 = ssrc[e], s1 = ssrc[e + 1];
    float x0 = xin[(size_t)s0 * DIM_H + lane];
    float x1 = xin[(size_t)s1 * DIM_H + lane];
    float m0 = fmaxf(x0, 0.f) + 1e-7f;
    float m1 = fmaxf(x1, 0.f) + 1e-7f;
    float e0 = __expf(tval * m0);
    float e1 = __expf(tval * m1);
    D0 += e0; S0 += m0 * e0;
    D1 += e1; S1 += m1 * e1;
  }
  if (e < end) {
    int s0 = ssrc[e];
    float x0 = xin[(size_t)s0 * DIM_H + lane];
    float m0 = fmaxf(x0, 0.f) + 1e-7f;
    float e0 = __expf(tval * m0);
    D0 += e0; S0 += m0 * e0;
  }
  float D = D0 + D1, S = S0 + S1;
  float agg = (end > beg) ? (S / D) : 0.f;
  float na = wsum(agg * agg);
  float nx = wsum(xv * xv);
  float msg = agg / fmaxf(sqrtf(na), 1e-12f);
  hmid[(size_t)v * DIM_H + lane] = xv + sc * msg * sqrtf(nx);
}

// ---------------- GENConv MLP + fused next pre-norm ----------------
// out = relu(LN(h@W1+b1))@W2+b2 (+res) -> hout; rnext = relu(LN(hout, gn, bn))
// Weights staged in 16KB k-halves through one buffer: LDS 40KB -> 4 blocks/CU
// (was 56KB -> 2 blocks/CU, 20% occupancy, VALUBusy 55%).

__global__ __launch_bounds__(256, 4) void k_mlp(const float* __restrict__ xin,
                                                const float* __restrict__ hres,
                                                float* __restrict__ hout,
                                                float* __restrict__ rnext,
                                                const float* __restrict__ W1,
                                                const float* __restrict__ b1,
                                                const float* __restrict__ g1,
                                                const float* __restrict__ bb1,
                                                const float* __restrict__ W2,
                                                const float* __restrict__ b2,
                                                const float* __restrict__ gn,
                                                const float* __restrict__ bn, int residual) {
  __shared__ float sWh[4096];           // 16KB: W1 k-halves, then W2 k-halves
  __shared__ float sx[32][DIM_H];       // 8KB
  __shared__ float su[32][DIM_H2];      // 16KB
  int t = threadIdx.x;
  int node0 = blockIdx.x * 32;
  // stage W1 rows k=0..31 (32x128) + activations
  for (int i = t; i < 4096; i += 256) sWh[i] = W1[i];
  for (int i = t; i < 32 * DIM_H; i += 256) {
    int r = i >> 6, c = i & 63;
    sx[r][c] = xin[(size_t)(node0 + r) * DIM_H + c];
  }
  __syncthreads();
  int w = t >> 6, lane = t & 63;
  float a0[8], a1[8];
#pragma unroll
  for (int j = 0; j < 8; j++) { a0[j] = 0.f; a1[j] = 0.f; }
#pragma unroll 2
  for (int half = 0; half < 2; half++) {
    if (half == 1) {
      __syncthreads();  // all reads of previous half done
      for (int i = t; i < 4096; i += 256) sWh[i] = W1[4096 + i];
      __syncthreads();
    }
    int kbase = half * 32;
    for (int k0 = 0; k0 < 32; k0 += 4) {
      float wa[4], wb[4];
#pragma unroll
      for (int q = 0; q < 4; q++) {
        wa[q] = sWh[(k0 + q) * DIM_H2 + lane];
        wb[q] = sWh[(k0 + q) * DIM_H2 + 64 + lane];
      }
#pragma unroll
      for (int j = 0; j < 8; j++) {
        float4 a = *(const float4*)&sx[w * 8 + j][kbase + k0];
        a0[j] += a.x * wa[0] + a.y * wa[1] + a.z * wa[2] + a.w * wa[3];
        a1[j] += a.x * wb[0] + a.y * wb[1] + a.z * wb[2] + a.w * wb[3];
      }
    }
  }
  float bias0 = b1[lane], bias1 = b1[64 + lane];
  float gg0 = g1[lane], gg1 = g1[64 + lane];
  float be0 = bb1[lane], be1 = bb1[64 + lane];
#pragma unroll
  for (int j = 0; j < 8; j++) {
    float u0 = a0[j] + bias0, u1 = a1[j] + bias1;
    float s = wsum(u0 + u1);
    float s2 = wsum(u0 * u0 + u1 * u1);
    float mu = s * (1.f / 128.f);
    float var = s2 * (1.f / 128.f) - mu * mu;
    float rs = rsqrtf(var + 1e-5f);
    u0 = fmaxf((u0 - mu) * rs * gg0 + be0, 0.f);
    u1 = fmaxf((u1 - mu) * rs * gg1 + be1, 0.f);
    su[w * 8 + j][lane] = u0;
    su[w * 8 + j][64 + lane] = u1;
  }
  float acc[8];
#pragma unroll
  for (int j = 0; j < 8; j++) acc[j] = 0.f;
#pragma unroll 2
  for (int half = 0; half < 2; half++) {
    __syncthreads();  // su complete (half 0) / prior W2 half reads done (half 1)
    for (int i = t; i < 4096; i += 256) sWh[i] = W2[half * 4096 + i];
    __syncthreads();
    int kbase = half * 64;
    for (int k0 = 0; k0 < 64; k0 += 4) {
      float wv[4];
#pragma unroll
      for (int q = 0; q < 4; q++) wv[q] = sWh[(k0 + q) * DIM_H + lane];
#pragma unroll
      for (int j = 0; j < 8; j++) {
        float4 a = *(const float4*)&su[w * 8 + j][kbase + k0];
        acc[j] += a.x * wv[0] + a.y * wv[1] + a.z * wv[2] + a.w * wv[3];
      }
    }
  }
  float b2v = b2[lane];
  float gv = gn[lane], bv = bn[lane];
#pragma unroll
  for (int j = 0; j < 8; j++) {
    int v = node0 + w * 8 + j;
    float o = acc[j] + b2v;
    if (residual) o += hres[(size_t)v * DIM_H + lane];
    hout[(size_t)v * DIM_H + lane] = o;
    // fused pre-norm for next stage: relu(LN(o, gn, bn))
    float s = wsum(o);
    float s2 = wsum(o * o);
    float mu = s * (1.f / 64.f);
    float var = s2 * (1.f / 64.f) - mu * mu;
    float rs = rsqrtf(var + 1e-5f);
    rnext[(size_t)v * DIM_H + lane] = fmaxf((o - mu) * rs * gv + bv, 0.f);
  }
}

// ---------------- final: out = rB @ lin_W + lin_b (rB pre-normed) ------------
// Spill-proof shape: thread = (channel c, 4-node group), NO per-thread arrays.

__global__ void k_final(const float* __restrict__ rB, const float* __restrict__ W,
                        const float* __restrict__ bias, float* __restrict__ out) {
  __shared__ float sW[DIM_H * DIM_OUT];  // 28KB
  __shared__ float sx[8][DIM_H];         // 2KB
  int t = threadIdx.x;
  int node0 = blockIdx.x * 8;
  for (int i = t; i < DIM_H * DIM_OUT; i += 256) sW[i] = W[i];
  for (int i = t; i < 8 * DIM_H; i += 256) sx[i >> 6][i & 63] = rB[(size_t)node0 * DIM_H + i];
  __syncthreads();
  int c = t & 127, g = t >> 7;
  int cc = (c < DIM_OUT) ? c : 0;  // keep inactive lanes in-bounds
  int r0 = g * 4;
  float a0 = 0.f, a1 = 0.f, a2 = 0.f, a3 = 0.f;
  for (int k = 0; k < DIM_H; ++k) {
    float wv = sW[k * DIM_OUT + cc];
    a0 += wv * sx[r0 + 0][k];
    a1 += wv * sx[r0 + 1][k];
    a2 += wv * sx[r0 + 2][k];
    a3 += wv * sx[r0 + 3][k];
  }
  if (c < DIM_OUT) {
    float bv = bias[c];
    out[(size_t)(node0 + r0 + 0) * DIM_OUT + c] = a0 + bv;
    out[(size_t)(node0 + r0 + 1) * DIM_OUT + c] = a1 + bv;
    out[(size_t)(node0 + r0 + 2) * DIM_OUT + c] = a2 + bv;
    out[(size_t)(node0 + r0 + 3) * DIM_OUT + c] = a3 + bv;
  }
}

// ---------------- launch ----------------

extern "C" void kernel_launch(void* const* d_in, const int* in_sizes, int n_in,
                              void* d_out, int out_size, void* d_ws, size_t ws_size,
                              hipStream_t stream) {
  const float* x = (const float*)d_in[0];
  const int* ei = (const int*)d_in[1];
  const float* encW = (const float*)d_in[2];
  const float* encb = (const float*)d_in[3];
  const float* t_arr = (const float*)d_in[4];
  const float* sc_arr = (const float*)d_in[5];
  const float* W1 = (const float*)d_in[6];
  const float* b1 = (const float*)d_in[7];
  const float* g1 = (const float*)d_in[8];
  const float* bb1 = (const float*)d_in[9];
  const float* W2 = (const float*)d_in[10];
  const float* b2 = (const float*)d_in[11];
  const float* ng = (const float*)d_in[12];
  const float* nbias = (const float*)d_in[13];
  const float* linW = (const float*)d_in[14];
  const float* linb = (const float*)d_in[15];

  float* hA = (float*)d_ws;                          // N*64 f32
  float* rB = hA + (size_t)N_NODES * DIM_H;          // N*64
  float* mC = rB + (size_t)N_NODES * DIM_H;          // N*64
  int* ssrc = (int*)(mC + (size_t)N_NODES * DIM_H);  // E
  int* offs = ssrc + N_EDGES;                        // N+1
  int* cursor = offs + (N_NODES + 1);                // N
  int* counts = cursor + N_NODES;                    // N
  int* bsums = counts + N_NODES;                     // <=512

  const int* srcI = ei;
  const int* dstI = ei + N_EDGES;

  const int nbScan = (N_NODES + 255) / 256;  // 391
  const int nbEdge = (N_EDGES + 255) / 256;  // 4688

  // CSR build (dst-sorted src list)
  k_zero_i<<<nbScan, 256, 0, stream>>>(counts, N_NODES);
  k_hist<<<nbEdge, 256, 0, stream>>>(dstI, counts);
  k_scan1<<<nbScan, 256, 0, stream>>>(counts, bsums);
  k_scan2<<<1, 512, 0, stream>>>(bsums, nbScan);
  k_scan3<<<nbScan, 256, 0, stream>>>(counts, bsums, offs);
  k_copy_i<<<nbScan, 256, 0, stream>>>(offs, cursor, N_NODES);
  k_scatter<<<nbEdge, 256, 0, stream>>>(srcI, dstI, cursor, ssrc);

  // encoder
  k_encoder<<<N_NODES / 32, 256, 0, stream>>>(x, encW, encb, hA);

  // layer 0: h = conv(h); fused epilogue emits rB = relu(LN(h, nrm_1))
  k_edge<<<N_NODES / 4, 256, 0, stream>>>(hA, ssrc, offs, t_arr, sc_arr, 0, mC);
  k_mlp<<<N_NODES / 32, 256, 0, stream>>>(mC, hA, hA, rB, W1, b1, g1, bb1, W2, b2,
                                          ng + 1 * DIM_H, nbias + 1 * DIM_H, 0);

  // layers 1..6: h = h + conv(rB); epilogue emits rB with nrm_{i+1} (nrm_0 after layer 6)
  for (int i = 1; i < N_LAYERS; i++) {
    int nx = (i + 1 < N_LAYERS) ? (i + 1) : 0;
    k_edge<<<N_NODES / 4, 256, 0, stream>>>(rB, ssrc, offs, t_arr, sc_arr, i, mC);
    k_mlp<<<N_NODES / 32, 256, 0, stream>>>(
        mC, hA, hA, rB, W1 + (size_t)i * DIM_H * DIM_H2, b1 + i * DIM_H2, g1 + i * DIM_H2,
        bb1 + i * DIM_H2, W2 + (size_t)i * DIM_H2 * DIM_H, b2 + i * DIM_H,
        ng + nx * DIM_H, nbias + nx * DIM_H, 1);
  }

  // final: rB already = relu(LN(h, nrm_0)); pure GEMM
  k_final<<<N_NODES / 8, 256, 0, stream>>>(rB, linW, linb, (float*)d_out);
}

// Round 6
// 12216.891 us; speedup vs baseline: 1.2099x; 1.2099x over previous
//
#include <hip/hip_runtime.h>

#define N_NODES 100000
#define N_EDGES 1200000
#define DIM_IN 128
#define DIM_H 64
#define DIM_H2 128
#define DIM_OUT 112
#define N_LAYERS 7

__device__ __forceinline__ float wsum(float v) {
#pragma unroll
  for (int m = 1; m < 64; m <<= 1) v += __shfl_xor(v, m, 64);
  return v;
}

// ---------------- preprocessing: CSR build (dst-sorted) ----------------

__global__ void k_zero_i(int* __restrict__ p, int n) {
  int i = blockIdx.x * 256 + threadIdx.x;
  if (i < n) p[i] = 0;
}

__global__ void k_hist(const int* __restrict__ dst, int* __restrict__ counts) {
  int e = blockIdx.x * 256 + threadIdx.x;
  if (e < N_EDGES) atomicAdd(&counts[dst[e]], 1);
}

__global__ void k_scan1(const int* __restrict__ counts, int* __restrict__ bsums) {
  __shared__ int sd[256];
  int t = threadIdx.x;
  int i = blockIdx.x * 256 + t;
  sd[t] = (i < N_NODES) ? counts[i] : 0;
  __syncthreads();
  for (int s = 128; s > 0; s >>= 1) {
    if (t < s) sd[t] += sd[t + s];
    __syncthreads();
  }
  if (t == 0) bsums[blockIdx.x] = sd[0];
}

__global__ void k_scan2(int* __restrict__ bsums, int nb) {
  __shared__ int sd[512];
  int t = threadIdx.x;
  int v = (t < nb) ? bsums[t] : 0;
  sd[t] = v;
  __syncthreads();
  for (int o = 1; o < 512; o <<= 1) {
    int add = (t >= o) ? sd[t - o] : 0;
    __syncthreads();
    sd[t] += add;
    __syncthreads();
  }
  if (t < nb) bsums[t] = sd[t] - v;  // exclusive
}

__global__ void k_scan3(const int* __restrict__ counts, const int* __restrict__ bsums,
                        int* __restrict__ offs) {
  __shared__ int sd[256];
  int t = threadIdx.x;
  int i = blockIdx.x * 256 + t;
  int v = (i < N_NODES) ? counts[i] : 0;
  sd[t] = v;
  __syncthreads();
  for (int o = 1; o < 256; o <<= 1) {
    int add = (t >= o) ? sd[t - o] : 0;
    __syncthreads();
    sd[t] += add;
    __syncthreads();
  }
  int excl = sd[t] - v + bsums[blockIdx.x];
  if (i < N_NODES) offs[i] = excl;
  if (i == N_NODES - 1) offs[N_NODES] = excl + v;  // = E
}

__global__ void k_copy_i(const int* __restrict__ a, int* __restrict__ b, int n) {
  int i = blockIdx.x * 256 + threadIdx.x;
  if (i < n) b[i] = a[i];
}

__global__ void k_scatter(const int* __restrict__ src, const int* __restrict__ dst,
                          int* __restrict__ cursor, int* __restrict__ ssrc) {
  int e = blockIdx.x * 256 + threadIdx.x;
  if (e < N_EDGES) {
    int d = dst[e];
    int p = atomicAdd(&cursor[d], 1);
    ssrc[p] = src[e];
  }
}

// ---------------- encoder: h = x @ enc_W + enc_b ----------------
// block 256 = 4 waves, 8 nodes/wave; W staged in LDS (32KB). grid = 3125.

__global__ __launch_bounds__(256, 3) void k_encoder(const float* __restrict__ x,
                                                    const float* __restrict__ W,
                                                    const float* __restrict__ bias,
                                                    float* __restrict__ h) {
  __shared__ float sx[32][DIM_IN];           // 16KB
  __shared__ float sW[DIM_IN * DIM_H];       // 32KB
  int t = threadIdx.x;
  int node0 = blockIdx.x * 32;
  for (int i = t; i < DIM_IN * DIM_H; i += 256) sW[i] = W[i];
  for (int i = t; i < 32 * DIM_IN; i += 256) {
    int r = i >> 7, c = i & 127;
    sx[r][c] = x[(size_t)(node0 + r) * DIM_IN + c];
  }
  __syncthreads();
  int w = t >> 6, lane = t & 63;
  float acc[8];
#pragma unroll
  for (int j = 0; j < 8; j++) acc[j] = 0.f;
  for (int k0 = 0; k0 < DIM_IN; k0 += 4) {
    float w0 = sW[(k0 + 0) * DIM_H + lane];
    float w1 = sW[(k0 + 1) * DIM_H + lane];
    float w2 = sW[(k0 + 2) * DIM_H + lane];
    float w3 = sW[(k0 + 3) * DIM_H + lane];
#pragma unroll
    for (int j = 0; j < 8; j++) {
      float4 a = *(const float4*)&sx[w * 8 + j][k0];
      acc[j] += a.x * w0 + a.y * w1 + a.z * w2 + a.w * w3;
    }
  }
  float bv = bias[lane];
#pragma unroll
  for (int j = 0; j < 8; j++) {
    int v = node0 + w * 8 + j;
    h[(size_t)v * DIM_H + lane] = acc[j] + bv;
  }
}

// ---------------- edge aggregation + MsgNorm ----------------
// wave per node, lane = channel. Per-channel softmax over in-edges is
// lane-local; skip max-subtraction (z = t*(relu(x)+eps) bounded ~8).

__global__ __launch_bounds__(256) void k_edge(const float* __restrict__ xin,
                                              const int* __restrict__ ssrc,
                                              const int* __restrict__ offs,
                                              const float* __restrict__ t_arr,
                                              const float* __restrict__ sc_arr, int layer,
                                              float* __restrict__ hmid) {
  int v = blockIdx.x * 4 + (threadIdx.x >> 6);
  int lane = threadIdx.x & 63;
  float tval = t_arr[layer];
  float sc = sc_arr[layer];
  int beg = offs[v], end = offs[v + 1];
  float xv = xin[(size_t)v * DIM_H + lane];
  float D0 = 0.f, S0 = 0.f, D1 = 0.f, S1 = 0.f;
  int e = beg;
  for (; e + 1 < end; e += 2) {
    int s0 = ssrc[e], s1 = ssrc[e + 1];
    float x0 = xin[(size_t)s0 * DIM_H + lane];
    float x1 = xin[(size_t)s1 * DIM_H + lane];
    float m0 = fmaxf(x0, 0.f) + 1e-7f;
    float m1 = fmaxf(x1, 0.f) + 1e-7f;
    float e0 = __expf(tval * m0);
    float e1 = __expf(tval * m1);
    D0 += e0; S0 += m0 * e0;
    D1 += e1; S1 += m1 * e1;
  }
  if (e < end) {
    int s0 = ssrc[e];
    float x0 = xin[(size_t)s0 * DIM_H + lane];
    float m0 = fmaxf(x0, 0.f) + 1e-7f;
    float e0 = __expf(tval * m0);
    D0 += e0; S0 += m0 * e0;
  }
  float D = D0 + D1, S = S0 + S1;
  float agg = (end > beg) ? (S / D) : 0.f;
  float na = wsum(agg * agg);
  float nx = wsum(xv * xv);
  float msg = agg / fmaxf(sqrtf(na), 1e-12f);
  hmid[(size_t)v * DIM_H + lane] = xv + sc * msg * sqrtf(nx);
}

// ---------------- GENConv MLP + fused next pre-norm ----------------
// out = relu(LN(h@W1+b1))@W2+b2 (+res) -> hout; rnext = relu(LN(hout, gn, bn))
// Weights staged in 16KB k-halves: LDS 40KB -> 4 blocks/CU (LDS-capped).
// __launch_bounds__(256,2): VGPR ceiling 256 — (256,4) forced VGPR=64 and
// catastrophic spill (R5: 3.7GB writes); (256,2) measured 88 VGPR, no spill,
// and 88 < 128 so HW still schedules 4 waves/SIMD. LDS, not bounds, caps us.

__global__ __launch_bounds__(256, 2) void k_mlp(const float* __restrict__ xin,
                                                const float* __restrict__ hres,
                                                float* __restrict__ hout,
                                                float* __restrict__ rnext,
                                                const float* __restrict__ W1,
                                                const float* __restrict__ b1,
                                                const float* __restrict__ g1,
                                                const float* __restrict__ bb1,
                                                const float* __restrict__ W2,
                                                const float* __restrict__ b2,
                                                const float* __restrict__ gn,
                                                const float* __restrict__ bn, int residual) {
  __shared__ float sWh[4096];           // 16KB: W1 k-halves, then W2 k-halves
  __shared__ float sx[32][DIM_H];       // 8KB
  __shared__ float su[32][DIM_H2];      // 16KB
  int t = threadIdx.x;
  int node0 = blockIdx.x * 32;
  // stage W1 rows k=0..31 (32x128) + activations
  for (int i = t; i < 4096; i += 256) sWh[i] = W1[i];
  for (int i = t; i < 32 * DIM_H; i += 256) {
    int r = i >> 6, c = i & 63;
    sx[r][c] = xin[(size_t)(node0 + r) * DIM_H + c];
  }
  __syncthreads();
  int w = t >> 6, lane = t & 63;
  float a0[8], a1[8];
#pragma unroll
  for (int j = 0; j < 8; j++) { a0[j] = 0.f; a1[j] = 0.f; }
#pragma unroll 2
  for (int half = 0; half < 2; half++) {
    if (half == 1) {
      __syncthreads();  // all reads of previous half done
      for (int i = t; i < 4096; i += 256) sWh[i] = W1[4096 + i];
      __syncthreads();
    }
    int kbase = half * 32;
    for (int k0 = 0; k0 < 32; k0 += 4) {
      float wa[4], wb[4];
#pragma unroll
      for (int q = 0; q < 4; q++) {
        wa[q] = sWh[(k0 + q) * DIM_H2 + lane];
        wb[q] = sWh[(k0 + q) * DIM_H2 + 64 + lane];
      }
#pragma unroll
      for (int j = 0; j < 8; j++) {
        float4 a = *(const float4*)&sx[w * 8 + j][kbase + k0];
        a0[j] += a.x * wa[0] + a.y * wa[1] + a.z * wa[2] + a.w * wa[3];
        a1[j] += a.x * wb[0] + a.y * wb[1] + a.z * wb[2] + a.w * wb[3];
      }
    }
  }
  float bias0 = b1[lane], bias1 = b1[64 + lane];
  float gg0 = g1[lane], gg1 = g1[64 + lane];
  float be0 = bb1[lane], be1 = bb1[64 + lane];
#pragma unroll
  for (int j = 0; j < 8; j++) {
    float u0 = a0[j] + bias0, u1 = a1[j] + bias1;
    float s = wsum(u0 + u1);
    float s2 = wsum(u0 * u0 + u1 * u1);
    float mu = s * (1.f / 128.f);
    float var = s2 * (1.f / 128.f) - mu * mu;
    float rs = rsqrtf(var + 1e-5f);
    u0 = fmaxf((u0 - mu) * rs * gg0 + be0, 0.f);
    u1 = fmaxf((u1 - mu) * rs * gg1 + be1, 0.f);
    su[w * 8 + j][lane] = u0;
    su[w * 8 + j][64 + lane] = u1;
  }
  float acc[8];
#pragma unroll
  for (int j = 0; j < 8; j++) acc[j] = 0.f;
#pragma unroll 2
  for (int half = 0; half < 2; half++) {
    __syncthreads();  // su complete (half 0) / prior W2 half reads done (half 1)
    for (int i = t; i < 4096; i += 256) sWh[i] = W2[half * 4096 + i];
    __syncthreads();
    int kbase = half * 64;
    for (int k0 = 0; k0 < 64; k0 += 4) {
      float wv[4];
#pragma unroll
      for (int q = 0; q < 4; q++) wv[q] = sWh[(k0 + q) * DIM_H + lane];
#pragma unroll
      for (int j = 0; j < 8; j++) {
        float4 a = *(const float4*)&su[w * 8 + j][kbase + k0];
        acc[j] += a.x * wv[0] + a.y * wv[1] + a.z * wv[2] + a.w * wv[3];
      }
    }
  }
  float b2v = b2[lane];
  float gv = gn[lane], bv = bn[lane];
#pragma unroll
  for (int j = 0; j < 8; j++) {
    int v = node0 + w * 8 + j;
    float o = acc[j] + b2v;
    if (residual) o += hres[(size_t)v * DIM_H + lane];
    hout[(size_t)v * DIM_H + lane] = o;
    // fused pre-norm for next stage: relu(LN(o, gn, bn))
    float s = wsum(o);
    float s2 = wsum(o * o);
    float mu = s * (1.f / 64.f);
    float var = s2 * (1.f / 64.f) - mu * mu;
    float rs = rsqrtf(var + 1e-5f);
    rnext[(size_t)v * DIM_H + lane] = fmaxf((o - mu) * rs * gv + bv, 0.f);
  }
}

// ---------------- final: out = rB @ lin_W + lin_b (rB pre-normed) ------------
// Spill-proof shape: thread = (channel c, 4-node group), NO per-thread arrays.

__global__ void k_final(const float* __restrict__ rB, const float* __restrict__ W,
                        const float* __restrict__ bias, float* __restrict__ out) {
  __shared__ float sW[DIM_H * DIM_OUT];  // 28KB
  __shared__ float sx[8][DIM_H];         // 2KB
  int t = threadIdx.x;
  int node0 = blockIdx.x * 8;
  for (int i = t; i < DIM_H * DIM_OUT; i += 256) sW[i] = W[i];
  for (int i = t; i < 8 * DIM_H; i += 256) sx[i >> 6][i & 63] = rB[(size_t)node0 * DIM_H + i];
  __syncthreads();
  int c = t & 127, g = t >> 7;
  int cc = (c < DIM_OUT) ? c : 0;  // keep inactive lanes in-bounds
  int r0 = g * 4;
  float a0 = 0.f, a1 = 0.f, a2 = 0.f, a3 = 0.f;
  for (int k = 0; k < DIM_H; ++k) {
    float wv = sW[k * DIM_OUT + cc];
    a0 += wv * sx[r0 + 0][k];
    a1 += wv * sx[r0 + 1][k];
    a2 += wv * sx[r0 + 2][k];
    a3 += wv * sx[r0 + 3][k];
  }
  if (c < DIM_OUT) {
    float bv = bias[c];
    out[(size_t)(node0 + r0 + 0) * DIM_OUT + c] = a0 + bv;
    out[(size_t)(node0 + r0 + 1) * DIM_OUT + c] = a1 + bv;
    out[(size_t)(node0 + r0 + 2) * DIM_OUT + c] = a2 + bv;
    out[(size_t)(node0 + r0 + 3) * DIM_OUT + c] = a3 + bv;
  }
}

// ---------------- launch ----------------

extern "C" void kernel_launch(void* const* d_in, const int* in_sizes, int n_in,
                              void* d_out, int out_size, void* d_ws, size_t ws_size,
                              hipStream_t stream) {
  const float* x = (const float*)d_in[0];
  const int* ei = (const int*)d_in[1];
  const float* encW = (const float*)d_in[2];
  const float* encb = (const float*)d_in[3];
  const float* t_arr = (const float*)d_in[4];
  const float* sc_arr = (const float*)d_in[5];
  const float* W1 = (const float*)d_in[6];
  const float* b1 = (const float*)d_in[7];
  const float* g1 = (const float*)d_in[8];
  const float* bb1 = (const float*)d_in[9];
  const float* W2 = (const float*)d_in[10];
  const float* b2 = (const float*)d_in[11];
  const float* ng = (const float*)d_in[12];
  const float* nbias = (const float*)d_in[13];
  const float* linW = (const float*)d_in[14];
  const float* linb = (const float*)d_in[15];

  float* hA = (float*)d_ws;                          // N*64 f32
  float* rB = hA + (size_t)N_NODES * DIM_H;          // N*64
  float* mC = rB + (size_t)N_NODES * DIM_H;          // N*64
  int* ssrc = (int*)(mC + (size_t)N_NODES * DIM_H);  // E
  int* offs = ssrc + N_EDGES;                        // N+1
  int* cursor = offs + (N_NODES + 1);                // N
  int* counts = cursor + N_NODES;                    // N
  int* bsums = counts + N_NODES;                     // <=512

  const int* srcI = ei;
  const int* dstI = ei + N_EDGES;

  const int nbScan = (N_NODES + 255) / 256;  // 391
  const int nbEdge = (N_EDGES + 255) / 256;  // 4688

  // CSR build (dst-sorted src list)
  k_zero_i<<<nbScan, 256, 0, stream>>>(counts, N_NODES);
  k_hist<<<nbEdge, 256, 0, stream>>>(dstI, counts);
  k_scan1<<<nbScan, 256, 0, stream>>>(counts, bsums);
  k_scan2<<<1, 512, 0, stream>>>(bsums, nbScan);
  k_scan3<<<nbScan, 256, 0, stream>>>(counts, bsums, offs);
  k_copy_i<<<nbScan, 256, 0, stream>>>(offs, cursor, N_NODES);
  k_scatter<<<nbEdge, 256, 0, stream>>>(srcI, dstI, cursor, ssrc);

  // encoder
  k_encoder<<<N_NODES / 32, 256, 0, stream>>>(x, encW, encb, hA);

  // layer 0: h = conv(h); fused epilogue emits rB = relu(LN(h, nrm_1))
  k_edge<<<N_NODES / 4, 256, 0, stream>>>(hA, ssrc, offs, t_arr, sc_arr, 0, mC);
  k_mlp<<<N_NODES / 32, 256, 0, stream>>>(mC, hA, hA, rB, W1, b1, g1, bb1, W2, b2,
                                          ng + 1 * DIM_H, nbias + 1 * DIM_H, 0);

  // layers 1..6: h = h + conv(rB); epilogue emits rB with nrm_{i+1} (nrm_0 after layer 6)
  for (int i = 1; i < N_LAYERS; i++) {
    int nx = (i + 1 < N_LAYERS) ? (i + 1) : 0;
    k_edge<<<N_NODES / 4, 256, 0, stream>>>(rB, ssrc, offs, t_arr, sc_arr, i, mC);
    k_mlp<<<N_NODES / 32, 256, 0, stream>>>(
        mC, hA, hA, rB, W1 + (size_t)i * DIM_H * DIM_H2, b1 + i * DIM_H2, g1 + i * DIM_H2,
        bb1 + i * DIM_H2, W2 + (size_t)i * DIM_H2 * DIM_H, b2 + i * DIM_H,
        ng + nx * DIM_H, nbias + nx * DIM_H, 1);
  }

  // final: rB already = relu(LN(h, nrm_0)); pure GEMM
  k_final<<<N_NODES / 8, 256, 0, stream>>>(rB, linW, linb, (float*)d_out);
}

// Round 7
// 1589.436 us; speedup vs baseline: 9.2999x; 7.6863x over previous
//
#include <hip/hip_runtime.h>

#define N_NODES 100000
#define N_EDGES 1200000
#define DIM_IN 128
#define DIM_H 64
#define DIM_H2 128
#define DIM_OUT 112
#define N_LAYERS 7

__device__ __forceinline__ float wsum(float v) {
#pragma unroll
  for (int m = 1; m < 64; m <<= 1) v += __shfl_xor(v, m, 64);
  return v;
}

// bf16 pack/unpack: bf16->f32 is just <<16 (bit ops, no cvt instruction)
__device__ __forceinline__ unsigned bf16rne(float f) {
  unsigned u = __float_as_uint(f);
  return (u + 0x7fffu + ((u >> 16) & 1u)) >> 16;
}
__device__ __forceinline__ unsigned pack2bf(float lo, float hi) {
  return bf16rne(lo) | (bf16rne(hi) << 16);
}
__device__ __forceinline__ float bflo(unsigned p) { return __uint_as_float(p << 16); }
__device__ __forceinline__ float bfhi(unsigned p) { return __uint_as_float(p & 0xffff0000u); }

// ---------------- preprocessing: CSR build (dst-sorted) ----------------

__global__ void k_zero_i(int* __restrict__ p, int n) {
  int i = blockIdx.x * 256 + threadIdx.x;
  if (i < n) p[i] = 0;
}

__global__ void k_hist(const int* __restrict__ dst, int* __restrict__ counts) {
  int e = blockIdx.x * 256 + threadIdx.x;
  if (e < N_EDGES) atomicAdd(&counts[dst[e]], 1);
}

__global__ void k_scan1(const int* __restrict__ counts, int* __restrict__ bsums) {
  __shared__ int sd[256];
  int t = threadIdx.x;
  int i = blockIdx.x * 256 + t;
  sd[t] = (i < N_NODES) ? counts[i] : 0;
  __syncthreads();
  for (int s = 128; s > 0; s >>= 1) {
    if (t < s) sd[t] += sd[t + s];
    __syncthreads();
  }
  if (t == 0) bsums[blockIdx.x] = sd[0];
}

__global__ void k_scan2(int* __restrict__ bsums, int nb) {
  __shared__ int sd[512];
  int t = threadIdx.x;
  int v = (t < nb) ? bsums[t] : 0;
  sd[t] = v;
  __syncthreads();
  for (int o = 1; o < 512; o <<= 1) {
    int add = (t >= o) ? sd[t - o] : 0;
    __syncthreads();
    sd[t] += add;
    __syncthreads();
  }
  if (t < nb) bsums[t] = sd[t] - v;  // exclusive
}

__global__ void k_scan3(const int* __restrict__ counts, const int* __restrict__ bsums,
                        int* __restrict__ offs) {
  __shared__ int sd[256];
  int t = threadIdx.x;
  int i = blockIdx.x * 256 + t;
  int v = (i < N_NODES) ? counts[i] : 0;
  sd[t] = v;
  __syncthreads();
  for (int o = 1; o < 256; o <<= 1) {
    int add = (t >= o) ? sd[t - o] : 0;
    __syncthreads();
    sd[t] += add;
    __syncthreads();
  }
  int excl = sd[t] - v + bsums[blockIdx.x];
  if (i < N_NODES) offs[i] = excl;
  if (i == N_NODES - 1) offs[N_NODES] = excl + v;  // = E
}

__global__ void k_copy_i(const int* __restrict__ a, int* __restrict__ b, int n) {
  int i = blockIdx.x * 256 + threadIdx.x;
  if (i < n) b[i] = a[i];
}

__global__ void k_scatter(const int* __restrict__ src, const int* __restrict__ dst,
                          int* __restrict__ cursor, int* __restrict__ ssrc) {
  int e = blockIdx.x * 256 + threadIdx.x;
  if (e < N_EDGES) {
    int d = dst[e];
    int p = atomicAdd(&cursor[d], 1);
    ssrc[p] = src[e];
  }
}

// ---------------- encoder: h = x @ enc_W + enc_b ----------------
// block 256 = 4 waves, 8 nodes/wave; W staged in LDS (32KB). grid = 3125.

__global__ __launch_bounds__(256, 3) void k_encoder(const float* __restrict__ x,
                                                    const float* __restrict__ W,
                                                    const float* __restrict__ bias,
                                                    float* __restrict__ h) {
  __shared__ float sx[32][DIM_IN];           // 16KB
  __shared__ float sW[DIM_IN * DIM_H];       // 32KB
  int t = threadIdx.x;
  int node0 = blockIdx.x * 32;
  for (int i = t; i < DIM_IN * DIM_H; i += 256) sW[i] = W[i];
  for (int i = t; i < 32 * DIM_IN; i += 256) {
    int r = i >> 7, c = i & 127;
    sx[r][c] = x[(size_t)(node0 + r) * DIM_IN + c];
  }
  __syncthreads();
  int w = t >> 6, lane = t & 63;
  float acc[8];
#pragma unroll
  for (int j = 0; j < 8; j++) acc[j] = 0.f;
  for (int k0 = 0; k0 < DIM_IN; k0 += 4) {
    float w0 = sW[(k0 + 0) * DIM_H + lane];
    float w1 = sW[(k0 + 1) * DIM_H + lane];
    float w2 = sW[(k0 + 2) * DIM_H + lane];
    float w3 = sW[(k0 + 3) * DIM_H + lane];
#pragma unroll
    for (int j = 0; j < 8; j++) {
      float4 a = *(const float4*)&sx[w * 8 + j][k0];
      acc[j] += a.x * w0 + a.y * w1 + a.z * w2 + a.w * w3;
    }
  }
  float bv = bias[lane];
#pragma unroll
  for (int j = 0; j < 8; j++) {
    int v = node0 + w * 8 + j;
    h[(size_t)v * DIM_H + lane] = acc[j] + bv;
  }
}

// ---------------- edge aggregation + MsgNorm ----------------
// wave per node, lane = channel. Per-channel softmax over in-edges is
// lane-local; skip max-subtraction (z = t*(relu(x)+eps) bounded ~8).

__global__ __launch_bounds__(256) void k_edge(const float* __restrict__ xin,
                                              const int* __restrict__ ssrc,
                                              const int* __restrict__ offs,
                                              const float* __restrict__ t_arr,
                                              const float* __restrict__ sc_arr, int layer,
                                              float* __restrict__ hmid) {
  int v = blockIdx.x * 4 + (threadIdx.x >> 6);
  int lane = threadIdx.x & 63;
  float tval = t_arr[layer];
  float sc = sc_arr[layer];
  int beg = offs[v], end = offs[v + 1];
  float xv = xin[(size_t)v * DIM_H + lane];
  float D0 = 0.f, S0 = 0.f, D1 = 0.f, S1 = 0.f;
  int e = beg;
  for (; e + 1 < end; e += 2) {
    int s0 = ssrc[e], s1 = ssrc[e + 1];
    float x0 = xin[(size_t)s0 * DIM_H + lane];
    float x1 = xin[(size_t)s1 * DIM_H + lane];
    float m0 = fmaxf(x0, 0.f) + 1e-7f;
    float m1 = fmaxf(x1, 0.f) + 1e-7f;
    float e0 = __expf(tval * m0);
    float e1 = __expf(tval * m1);
    D0 += e0; S0 += m0 * e0;
    D1 += e1; S1 += m1 * e1;
  }
  if (e < end) {
    int s0 = ssrc[e];
    float x0 = xin[(size_t)s0 * DIM_H + lane];
    float m0 = fmaxf(x0, 0.f) + 1e-7f;
    float e0 = __expf(tval * m0);
    D0 += e0; S0 += m0 * e0;
  }
  float D = D0 + D1, S = S0 + S1;
  float agg = (end > beg) ? (S / D) : 0.f;
  float na = wsum(agg * agg);
  float nx = wsum(xv * xv);
  float msg = agg / fmaxf(sqrtf(na), 1e-12f);
  hmid[(size_t)v * DIM_H + lane] = xv + sc * msg * sqrtf(nx);
}

// ---------------- GENConv MLP + fused next pre-norm ----------------
// out = relu(LN(h@W1+b1))@W2+b2 (+res) -> hout; rnext = relu(LN(hout, gn, bn))
// R4's proven loop skeleton (single W2 restage, (256,2): VGPR 88, zero spill).
// Weights held in LDS as PACKED BF16 PAIRS (uint = 2 bf16 along k):
// sWp 16KB + sx 8KB + su 16KB = 40KB -> 4 blocks/CU (160KB exactly), 16 waves.
// NOTE: do NOT split staging into multi-restage half-loops and do NOT raise
// min-waves in launch_bounds — both variants spilled catastrophically (R5/R6).

__global__ __launch_bounds__(256, 2) void k_mlp(const float* __restrict__ xin,
                                                const float* __restrict__ hres,
                                                float* __restrict__ hout,
                                                float* __restrict__ rnext,
                                                const float* __restrict__ W1,
                                                const float* __restrict__ b1,
                                                const float* __restrict__ g1,
                                                const float* __restrict__ bb1,
                                                const float* __restrict__ W2,
                                                const float* __restrict__ b2,
                                                const float* __restrict__ gn,
                                                const float* __restrict__ bn, int residual) {
  __shared__ unsigned sWp[4096];        // 16KB: W1 as bf16 pairs, then W2
  __shared__ float sx[32][DIM_H];       // 8KB
  __shared__ float su[32][DIM_H2];      // 16KB
  int t = threadIdx.x;
  int node0 = blockIdx.x * 32;
  // stage W1 packed: sWp[kp*128 + c] = (bf(W1[2kp+1][c])<<16) | bf(W1[2kp][c])
  for (int i = t; i < 4096; i += 256) {
    int c = i & 127, kp = i >> 7;  // consecutive t -> consecutive c: coalesced
    sWp[i] = pack2bf(W1[(size_t)(2 * kp) * DIM_H2 + c], W1[(size_t)(2 * kp + 1) * DIM_H2 + c]);
  }
  for (int i = t; i < 32 * DIM_H; i += 256) {
    int r = i >> 6, c = i & 63;
    sx[r][c] = xin[(size_t)(node0 + r) * DIM_H + c];
  }
  __syncthreads();
  int w = t >> 6, lane = t & 63;
  float a0[8], a1[8];
#pragma unroll
  for (int j = 0; j < 8; j++) { a0[j] = 0.f; a1[j] = 0.f; }
  for (int k0 = 0; k0 < DIM_H; k0 += 4) {
    int kp = k0 >> 1;
    unsigned pa0 = sWp[kp * 128 + lane];
    unsigned pa1 = sWp[(kp + 1) * 128 + lane];
    unsigned pb0 = sWp[kp * 128 + 64 + lane];
    unsigned pb1 = sWp[(kp + 1) * 128 + 64 + lane];
    float wa0 = bflo(pa0), wa1 = bfhi(pa0), wa2 = bflo(pa1), wa3 = bfhi(pa1);
    float wb0 = bflo(pb0), wb1 = bfhi(pb0), wb2 = bflo(pb1), wb3 = bfhi(pb1);
#pragma unroll
    for (int j = 0; j < 8; j++) {
      float4 a = *(const float4*)&sx[w * 8 + j][k0];
      a0[j] += a.x * wa0 + a.y * wa1 + a.z * wa2 + a.w * wa3;
      a1[j] += a.x * wb0 + a.y * wb1 + a.z * wb2 + a.w * wb3;
    }
  }
  float bias0 = b1[lane], bias1 = b1[64 + lane];
  float gg0 = g1[lane], gg1 = g1[64 + lane];
  float be0 = bb1[lane], be1 = bb1[64 + lane];
#pragma unroll
  for (int j = 0; j < 8; j++) {
    float u0 = a0[j] + bias0, u1 = a1[j] + bias1;
    float s = wsum(u0 + u1);
    float s2 = wsum(u0 * u0 + u1 * u1);
    float mu = s * (1.f / 128.f);
    float var = s2 * (1.f / 128.f) - mu * mu;
    float rs = rsqrtf(var + 1e-5f);
    u0 = fmaxf((u0 - mu) * rs * gg0 + be0, 0.f);
    u1 = fmaxf((u1 - mu) * rs * gg1 + be1, 0.f);
    su[w * 8 + j][lane] = u0;
    su[w * 8 + j][64 + lane] = u1;
  }
  __syncthreads();  // all GEMM1 sWp reads + su writes done
  // stage W2 packed: sWp[kp*64 + c], kp in [0,64)
  for (int i = t; i < 4096; i += 256) {
    int c = i & 63, kp = i >> 6;
    sWp[i] = pack2bf(W2[(size_t)(2 * kp) * DIM_H + c], W2[(size_t)(2 * kp + 1) * DIM_H + c]);
  }
  __syncthreads();
  float acc[8];
#pragma unroll
  for (int j = 0; j < 8; j++) acc[j] = 0.f;
  for (int k0 = 0; k0 < DIM_H2; k0 += 4) {
    int kp = k0 >> 1;
    unsigned p0 = sWp[kp * 64 + lane];
    unsigned p1 = sWp[(kp + 1) * 64 + lane];
    float wv0 = bflo(p0), wv1 = bfhi(p0), wv2 = bflo(p1), wv3 = bfhi(p1);
#pragma unroll
    for (int j = 0; j < 8; j++) {
      float4 a = *(const float4*)&su[w * 8 + j][k0];
      acc[j] += a.x * wv0 + a.y * wv1 + a.z * wv2 + a.w * wv3;
    }
  }
  float b2v = b2[lane];
  float gv = gn[lane], bv = bn[lane];
#pragma unroll
  for (int j = 0; j < 8; j++) {
    int v = node0 + w * 8 + j;
    float o = acc[j] + b2v;
    if (residual) o += hres[(size_t)v * DIM_H + lane];
    hout[(size_t)v * DIM_H + lane] = o;
    // fused pre-norm for next stage: relu(LN(o, gn, bn))
    float s = wsum(o);
    float s2 = wsum(o * o);
    float mu = s * (1.f / 64.f);
    float var = s2 * (1.f / 64.f) - mu * mu;
    float rs = rsqrtf(var + 1e-5f);
    rnext[(size_t)v * DIM_H + lane] = fmaxf((o - mu) * rs * gv + bv, 0.f);
  }
}

// ---------------- final: out = rB @ lin_W + lin_b (rB pre-normed) ------------
// Spill-proof shape: thread = (channel c, 4-node group), NO per-thread arrays.

__global__ void k_final(const float* __restrict__ rB, const float* __restrict__ W,
                        const float* __restrict__ bias, float* __restrict__ out) {
  __shared__ float sW[DIM_H * DIM_OUT];  // 28KB
  __shared__ float sx[8][DIM_H];         // 2KB
  int t = threadIdx.x;
  int node0 = blockIdx.x * 8;
  for (int i = t; i < DIM_H * DIM_OUT; i += 256) sW[i] = W[i];
  for (int i = t; i < 8 * DIM_H; i += 256) sx[i >> 6][i & 63] = rB[(size_t)node0 * DIM_H + i];
  __syncthreads();
  int c = t & 127, g = t >> 7;
  int cc = (c < DIM_OUT) ? c : 0;  // keep inactive lanes in-bounds
  int r0 = g * 4;
  float a0 = 0.f, a1 = 0.f, a2 = 0.f, a3 = 0.f;
  for (int k = 0; k < DIM_H; ++k) {
    float wv = sW[k * DIM_OUT + cc];
    a0 += wv * sx[r0 + 0][k];
    a1 += wv * sx[r0 + 1][k];
    a2 += wv * sx[r0 + 2][k];
    a3 += wv * sx[r0 + 3][k];
  }
  if (c < DIM_OUT) {
    float bv = bias[c];
    out[(size_t)(node0 + r0 + 0) * DIM_OUT + c] = a0 + bv;
    out[(size_t)(node0 + r0 + 1) * DIM_OUT + c] = a1 + bv;
    out[(size_t)(node0 + r0 + 2) * DIM_OUT + c] = a2 + bv;
    out[(size_t)(node0 + r0 + 3) * DIM_OUT + c] = a3 + bv;
  }
}

// ---------------- launch ----------------

extern "C" void kernel_launch(void* const* d_in, const int* in_sizes, int n_in,
                              void* d_out, int out_size, void* d_ws, size_t ws_size,
                              hipStream_t stream) {
  const float* x = (const float*)d_in[0];
  const int* ei = (const int*)d_in[1];
  const float* encW = (const float*)d_in[2];
  const float* encb = (const float*)d_in[3];
  const float* t_arr = (const float*)d_in[4];
  const float* sc_arr = (const float*)d_in[5];
  const float* W1 = (const float*)d_in[6];
  const float* b1 = (const float*)d_in[7];
  const float* g1 = (const float*)d_in[8];
  const float* bb1 = (const float*)d_in[9];
  const float* W2 = (const float*)d_in[10];
  const float* b2 = (const float*)d_in[11];
  const float* ng = (const float*)d_in[12];
  const float* nbias = (const float*)d_in[13];
  const float* linW = (const float*)d_in[14];
  const float* linb = (const float*)d_in[15];

  float* hA = (float*)d_ws;                          // N*64 f32
  float* rB = hA + (size_t)N_NODES * DIM_H;          // N*64
  float* mC = rB + (size_t)N_NODES * DIM_H;          // N*64
  int* ssrc = (int*)(mC + (size_t)N_NODES * DIM_H);  // E
  int* offs = ssrc + N_EDGES;                        // N+1
  int* cursor = offs + (N_NODES + 1);                // N
  int* counts = cursor + N_NODES;                    // N
  int* bsums = counts + N_NODES;                     // <=512

  const int* srcI = ei;
  const int* dstI = ei + N_EDGES;

  const int nbScan = (N_NODES + 255) / 256;  // 391
  const int nbEdge = (N_EDGES + 255) / 256;  // 4688

  // CSR build (dst-sorted src list)
  k_zero_i<<<nbScan, 256, 0, stream>>>(counts, N_NODES);
  k_hist<<<nbEdge, 256, 0, stream>>>(dstI, counts);
  k_scan1<<<nbScan, 256, 0, stream>>>(counts, bsums);
  k_scan2<<<1, 512, 0, stream>>>(bsums, nbScan);
  k_scan3<<<nbScan, 256, 0, stream>>>(counts, bsums, offs);
  k_copy_i<<<nbScan, 256, 0, stream>>>(offs, cursor, N_NODES);
  k_scatter<<<nbEdge, 256, 0, stream>>>(srcI, dstI, cursor, ssrc);

  // encoder
  k_encoder<<<N_NODES / 32, 256, 0, stream>>>(x, encW, encb, hA);

  // layer 0: h = conv(h); fused epilogue emits rB = relu(LN(h, nrm_1))
  k_edge<<<N_NODES / 4, 256, 0, stream>>>(hA, ssrc, offs, t_arr, sc_arr, 0, mC);
  k_mlp<<<N_NODES / 32, 256, 0, stream>>>(mC, hA, hA, rB, W1, b1, g1, bb1, W2, b2,
                                          ng + 1 * DIM_H, nbias + 1 * DIM_H, 0);

  // layers 1..6: h = h + conv(rB); epilogue emits rB with nrm_{i+1} (nrm_0 after layer 6)
  for (int i = 1; i < N_LAYERS; i++) {
    int nx = (i + 1 < N_LAYERS) ? (i + 1) : 0;
    k_edge<<<N_NODES / 4, 256, 0, stream>>>(rB, ssrc, offs, t_arr, sc_arr, i, mC);
    k_mlp<<<N_NODES / 32, 256, 0, stream>>>(
        mC, hA, hA, rB, W1 + (size_t)i * DIM_H * DIM_H2, b1 + i * DIM_H2, g1 + i * DIM_H2,
        bb1 + i * DIM_H2, W2 + (size_t)i * DIM_H2 * DIM_H, b2 + i * DIM_H,
        ng + nx * DIM_H, nbias + nx * DIM_H, 1);
  }

  // final: rB already = relu(LN(h, nrm_0)); pure GEMM
  k_final<<<N_NODES / 8, 256, 0, stream>>>(rB, linW, linb, (float*)d_out);
}